// Round 4
// baseline (48.539 us; speedup 1.0000x reference)
//
#include <hip/hip_runtime.h>

// GeometryKernelAttention: nearest-neighbor multi-scale gather + weighted sum.
// B=1, NQ=20000, H=8, L=4, P=8, D=32, NUM_VALUE=19560.
// Output: (1, 20000, 256) f32, returned twice (concatenated in d_out).
//
// R2: head<->XCD affinity (blockIdx%8 == head) -> per-head value slice lives
//     in its XCD's L2. FETCH_SIZE hit the 50 MB ideal.
// R3: LDS (f,w) staging — neutral -> not front-end bound; L2 gather-path bound.
// R4: halve gather bytes: convert value to bf16 in d_ws (per launch), gather
//     64-B rows (ushort4/lane), f32 accumulate. Batched loads (8 in flight).

#define GKA_NQ       20000
#define GKA_H        8
#define GKA_NV       19560
#define GKA_NVAL     5007360   // NV * 8 * 32
#define GKA_OUT_HALF 5120000   // 20000 * 256

static __device__ __forceinline__ unsigned short f2bf(float x) {
    unsigned u = __float_as_uint(x);
    unsigned r = 0x7FFFu + ((u >> 16) & 1u);   // round-to-nearest-even
    return (unsigned short)((u + r) >> 16);
}
static __device__ __forceinline__ float bf2f(unsigned short b) {
    return __uint_as_float(((unsigned)b) << 16);
}

__global__ __launch_bounds__(256) void gka_conv(
    const float* __restrict__ v, ushort* __restrict__ o)
{
    const int n4 = GKA_NVAL / 4;
    for (int i = blockIdx.x * 256 + threadIdx.x; i < n4; i += gridDim.x * 256) {
        const float4 f = ((const float4*)v)[i];
        ushort4 b;
        b.x = f2bf(f.x); b.y = f2bf(f.y); b.z = f2bf(f.z); b.w = f2bf(f.w);
        ((ushort4*)o)[i] = b;
    }
}

__global__ __launch_bounds__(256) void gka_kernel_bf16(
    const ushort* __restrict__ value,  // [NV, 8, 32] bf16 (in d_ws)
    const float* __restrict__ sloc,    // [NQ, 8, 4, 8, 2]
    const float* __restrict__ awgt,    // [NQ, 8, 4, 8]
    float* __restrict__ out)           // [2, NQ, 256]
{
    __shared__ uint2 fw[32][34];

    const int tid  = threadIdx.x;
    const int lane = tid & 63;
    const int wave = tid >> 6;
    const int h      = blockIdx.x & 7;         // head == XCD (round-robin dispatch)
    const int qchunk = blockIdx.x >> 3;
    const int qq   = lane >> 3;
    const int sub  = lane & 7;
    const int qloc = wave * 8 + qq;
    const int q    = qchunk * 32 + qloc;

    // ---- Phase A: compute 4 (flat, w) pairs; 4 samples share one level ----
    const int lvl = sub >> 1;
    const int Wi  = (lvl == 0) ? 160 : (lvl == 1) ? 80 : (lvl == 2) ? 40 : 20;
    const int Hi  = (lvl == 0) ? 92  : (lvl == 1) ? 46 : (lvl == 2) ? 23 : 12;
    const int ls  = (lvl == 0) ? 0   : (lvl == 1) ? 14720 : (lvl == 2) ? 18400 : 19320;
    const float Wf = (float)Wi;
    const float Hf = (float)Hi;

    const int qh = q * GKA_H + h;
    const float4* lp = (const float4*)(sloc + (size_t)qh * 64 + sub * 8);
    const float4 xy0 = lp[0];
    const float4 xy1 = lp[1];
    const float4 w4  = *(const float4*)(awgt + (size_t)qh * 32 + sub * 4);

    {
        const float xs[4] = {xy0.x, xy0.z, xy1.x, xy1.z};
        const float ys[4] = {xy0.y, xy0.w, xy1.y, xy1.w};
        const float ws[4] = {w4.x, w4.y, w4.z, w4.w};
        #pragma unroll
        for (int k = 0; k < 4; ++k) {
            const int col = (int)floorf(xs[k] * Wf);
            const int row = (int)floorf(ys[k] * Hf);
            const bool valid = (col >= 0) & (col < Wi) & (row >= 0) & (row < Hi);
            int f = ls + row * Wi + col;
            f = min(max(f, 0), GKA_NV - 1);
            const float wv = valid ? ws[k] : 0.0f;
            fw[qloc][4 * sub + k] = make_uint2((unsigned)f, __float_as_uint(wv));
        }
    }

    __syncthreads();

    // ---- Phase B: batched bf16 gather (8 loads in flight) + f32 FMA ----
    float4 acc = make_float4(0.f, 0.f, 0.f, 0.f);
    const ushort* vbase = value + h * 32 + sub * 4;   // + flat*256 per sample
    const uint4* row = (const uint4*)(&fw[qloc][0]);  // 2 (f,w) pairs per uint4

    #pragma unroll
    for (int b = 0; b < 4; ++b) {
        uint4 p[4];
        #pragma unroll
        for (int t = 0; t < 4; ++t) p[t] = row[b * 4 + t];

        ushort4 v[8];
        #pragma unroll
        for (int t = 0; t < 4; ++t) {
            v[2 * t]     = *(const ushort4*)(vbase + (size_t)p[t].x * 256);
            v[2 * t + 1] = *(const ushort4*)(vbase + (size_t)p[t].z * 256);
        }
        #pragma unroll
        for (int t = 0; t < 4; ++t) {
            const float w0 = __uint_as_float(p[t].y);
            const float w1 = __uint_as_float(p[t].w);
            acc.x = fmaf(w0, bf2f(v[2 * t].x), acc.x);
            acc.y = fmaf(w0, bf2f(v[2 * t].y), acc.y);
            acc.z = fmaf(w0, bf2f(v[2 * t].z), acc.z);
            acc.w = fmaf(w0, bf2f(v[2 * t].w), acc.w);
            acc.x = fmaf(w1, bf2f(v[2 * t + 1].x), acc.x);
            acc.y = fmaf(w1, bf2f(v[2 * t + 1].y), acc.y);
            acc.z = fmaf(w1, bf2f(v[2 * t + 1].z), acc.z);
            acc.w = fmaf(w1, bf2f(v[2 * t + 1].w), acc.w);
        }
    }

    float* o = out + (size_t)q * 256 + h * 32 + sub * 4;
    *(float4*)o = acc;
    *(float4*)(o + GKA_OUT_HALF) = acc;
}

// Fallback: proven R3 f32-gather path (used only if ws_size too small).
__global__ __launch_bounds__(256) void gka_kernel_f32(
    const float* __restrict__ value,
    const float* __restrict__ sloc,
    const float* __restrict__ awgt,
    float* __restrict__ out)
{
    __shared__ uint2 fw[32][34];

    const int tid  = threadIdx.x;
    const int lane = tid & 63;
    const int wave = tid >> 6;
    const int h      = blockIdx.x & 7;
    const int qchunk = blockIdx.x >> 3;
    const int qq   = lane >> 3;
    const int sub  = lane & 7;
    const int qloc = wave * 8 + qq;
    const int q    = qchunk * 32 + qloc;

    const int lvl = sub >> 1;
    const int Wi  = (lvl == 0) ? 160 : (lvl == 1) ? 80 : (lvl == 2) ? 40 : 20;
    const int Hi  = (lvl == 0) ? 92  : (lvl == 1) ? 46 : (lvl == 2) ? 23 : 12;
    const int ls  = (lvl == 0) ? 0   : (lvl == 1) ? 14720 : (lvl == 2) ? 18400 : 19320;
    const float Wf = (float)Wi;
    const float Hf = (float)Hi;

    const int qh = q * GKA_H + h;
    const float4* lp = (const float4*)(sloc + (size_t)qh * 64 + sub * 8);
    const float4 xy0 = lp[0];
    const float4 xy1 = lp[1];
    const float4 w4  = *(const float4*)(awgt + (size_t)qh * 32 + sub * 4);

    {
        const float xs[4] = {xy0.x, xy0.z, xy1.x, xy1.z};
        const float ys[4] = {xy0.y, xy0.w, xy1.y, xy1.w};
        const float ws[4] = {w4.x, w4.y, w4.z, w4.w};
        #pragma unroll
        for (int k = 0; k < 4; ++k) {
            const int col = (int)floorf(xs[k] * Wf);
            const int row = (int)floorf(ys[k] * Hf);
            const bool valid = (col >= 0) & (col < Wi) & (row >= 0) & (row < Hi);
            int f = ls + row * Wi + col;
            f = min(max(f, 0), GKA_NV - 1);
            const float wv = valid ? ws[k] : 0.0f;
            fw[qloc][4 * sub + k] = make_uint2((unsigned)f, __float_as_uint(wv));
        }
    }

    __syncthreads();

    float4 acc = make_float4(0.f, 0.f, 0.f, 0.f);
    const float* vbase = value + h * 32 + sub * 4;
    const uint4* row = (const uint4*)(&fw[qloc][0]);
    #pragma unroll
    for (int jj = 0; jj < 16; ++jj) {
        const uint4 pw = row[jj];
        {
            const float4 v = *(const float4*)(vbase + (size_t)pw.x * 256);
            const float w = __uint_as_float(pw.y);
            acc.x = fmaf(w, v.x, acc.x);
            acc.y = fmaf(w, v.y, acc.y);
            acc.z = fmaf(w, v.z, acc.z);
            acc.w = fmaf(w, v.w, acc.w);
        }
        {
            const float4 v = *(const float4*)(vbase + (size_t)pw.z * 256);
            const float w = __uint_as_float(pw.w);
            acc.x = fmaf(w, v.x, acc.x);
            acc.y = fmaf(w, v.y, acc.y);
            acc.z = fmaf(w, v.z, acc.z);
            acc.w = fmaf(w, v.w, acc.w);
        }
    }

    float* o = out + (size_t)q * 256 + h * 32 + sub * 4;
    *(float4*)o = acc;
    *(float4*)(o + GKA_OUT_HALF) = acc;
}

extern "C" void kernel_launch(void* const* d_in, const int* in_sizes, int n_in,
                              void* d_out, int out_size, void* d_ws, size_t ws_size,
                              hipStream_t stream) {
    const float* value = (const float*)d_in[0];
    const float* sloc  = (const float*)d_in[3];
    const float* awgt  = (const float*)d_in[4];
    float* out = (float*)d_out;

    dim3 grid((GKA_NQ / 32) * GKA_H);   // blockIdx % 8 == head -> XCD affinity

    if (ws_size >= (size_t)GKA_NVAL * sizeof(ushort)) {
        ushort* vbf = (ushort*)d_ws;
        gka_conv<<<1024, 256, 0, stream>>>(value, vbf);
        gka_kernel_bf16<<<grid, 256, 0, stream>>>(vbf, sloc, awgt, out);
    } else {
        gka_kernel_f32<<<grid, 256, 0, stream>>>(value, sloc, awgt, out);
    }
}